// Round 5
// baseline (4258.662 us; speedup 1.0000x reference)
//
#include <hip/hip_runtime.h>

#define TT 2048
#define HD 64

// LDS arena byte map:
//   h1 : [0, 2048)      parity p, row r at (p*4+r)*256 B; 16B blocks XOR-swizzled
//   h2 : [2112, 4160)   same layout, +64B skew so h1+h2 chunk reads cover all 32 banks
//   fcs: [4160, 5184)
#define H1_BASE 0
#define H2_BASE 2112
#define FCS_BASE 4160

__device__ __forceinline__ float fsig(float x)  { return 1.0f / (1.0f + __expf(-x)); }
__device__ __forceinline__ float ftanh_(float x){ return 1.0f - 2.0f / (1.0f + __expf(2.0f * x)); }

// 16B-block swizzle within a 256B row: block index b in [0,16) -> byte offset
__device__ __forceinline__ int swz(int b) { return ((b ^ ((b >> 2) & 3)) << 4); }

// Pin a float4 into VGPRs: opaque to the optimizer, so the original global
// load can NOT be rematerialized/sunk into the loop. (R4: VGPR=84 proved the
// compiler was re-loading all weights from L2 every step.)
#define PIN4(v) asm volatile("" : "+v"(v.x), "+v"(v.y), "+v"(v.z), "+v"(v.w))
#define PIN1(v) asm volatile("" : "+v"(v))

// DPP quad_perm add: pure VALU cross-lane, stays OFF the LDS pipe.
// 0xB1 = quad_perm[1,0,3,2] (xor 1), 0x4E = quad_perm[2,3,0,1] (xor 2).
template<int CTRL>
__device__ __forceinline__ float dpp_add(float v) {
    const int o = __builtin_amdgcn_update_dpp(0, __float_as_int(v), CTRL, 0xF, 0xF, true);
    return v + __int_as_float(o);
}
#define BF2D(v) { v = dpp_add<0xB1>(v); v = dpp_add<0x4E>(v); }

#define DOT16(acc, W0, W1, W2, W3) \
    acc = __fmaf_rn(W0.x, hv0.x, acc); acc = __fmaf_rn(W0.y, hv0.y, acc); \
    acc = __fmaf_rn(W0.z, hv0.z, acc); acc = __fmaf_rn(W0.w, hv0.w, acc); \
    acc = __fmaf_rn(W1.x, hv1.x, acc); acc = __fmaf_rn(W1.y, hv1.y, acc); \
    acc = __fmaf_rn(W1.z, hv1.z, acc); acc = __fmaf_rn(W1.w, hv1.w, acc); \
    acc = __fmaf_rn(W2.x, hv2.x, acc); acc = __fmaf_rn(W2.y, hv2.y, acc); \
    acc = __fmaf_rn(W2.z, hv2.z, acc); acc = __fmaf_rn(W2.w, hv2.w, acc); \
    acc = __fmaf_rn(W3.x, hv3.x, acc); acc = __fmaf_rn(W3.y, hv3.y, acc); \
    acc = __fmaf_rn(W3.z, hv3.z, acc); acc = __fmaf_rn(W3.w, hv3.w, acc);

#define ROWDOT(R, A0, A1, A2, A3) { \
    const float4 hv0 = *(const float4*)(rp + (R)*256 + o0); \
    const float4 hv1 = *(const float4*)(rp + (R)*256 + o1); \
    const float4 hv2 = *(const float4*)(rp + (R)*256 + o2); \
    const float4 hv3 = *(const float4*)(rp + (R)*256 + o3); \
    DOT16(A0, wA0, wA1, wA2, wA3); \
    DOT16(A1, wB0, wB1, wB2, wB3); \
    DOT16(A2, wC0, wC1, wC2, wC3); \
    DOT16(A3, wD0, wD1, wD2, wD3); }

// pick row=rk value out of the 4 row-accumulators (all lanes hold quad/full sums)
#define SEL4(e, x0, x1, x2, x3) \
    float e = x0; e = (rk == 1) ? x1 : e; e = (rk == 2) ? x2 : e; e = (rk == 3) ? x3 : e;

// Block = 768 threads, 4 batch rows per block.
//   waves 0-3  (tid 0..255):   layer0.  j=tid>>2 (unit), ck=tid&3  (16-wide K chunk of 64)
//   waves 4-11 (tid 256..767): layer1.  p=tid-256, j=p>>3, ck=p&7 (16-wide chunk of K=128=[h1|h2])
// Reduction: xor1+xor2 via DPP quad_perm (VALU); L1's xor4 via 4 ds_swizzle AFTER row-select.
// Pipeline: iter i does layer0 step i and layer1 step i-1; ONE barrier per iter.
__global__ __launch_bounds__(768, 3)
void lstm2_kernel(const float* __restrict__ x,
                  const float* __restrict__ Wih0,
                  const float* __restrict__ Whh0,
                  const float* __restrict__ bih0,
                  const float* __restrict__ bhh0,
                  const float* __restrict__ Wih1,
                  const float* __restrict__ Whh1,
                  const float* __restrict__ bih1,
                  const float* __restrict__ bhh1,
                  const float* __restrict__ fcW,
                  const float* __restrict__ fcb,
                  float* __restrict__ out)
{
    __shared__ __align__(16) float arena_f[1296];
    char* const arena = (char*)arena_f;

    const int tid  = threadIdx.x;
    const int row0 = blockIdx.x * 4;

    const bool isL0 = (tid < 256);
    const int  p    = isL0 ? tid : (tid - 256);
    const int  j    = isL0 ? (p >> 2) : (p >> 3);
    const int  ck   = isL0 ? (p & 3)  : (p & 7);
    const int  ckk  = (ck < 4) ? ck : (ck - 4);
    const int  rk   = ck & 3;                      // this lane's output row

    // ---- weights: 16 explicit float4 registers (64 VGPRs), no arrays ----
    const float* Wsrc;
    if (isL0)        Wsrc = Whh0;
    else if (ck < 4) Wsrc = Wih1;
    else             Wsrc = Whh1;
    const int kbase = 16 * ckk;
    const float4* W0p = (const float4*)(Wsrc + (0 * HD + j) * HD + kbase);
    const float4* W1p = (const float4*)(Wsrc + (1 * HD + j) * HD + kbase);
    const float4* W2p = (const float4*)(Wsrc + (2 * HD + j) * HD + kbase);
    const float4* W3p = (const float4*)(Wsrc + (3 * HD + j) * HD + kbase);
    float4 wA0 = W0p[0], wA1 = W0p[1], wA2 = W0p[2], wA3 = W0p[3];
    float4 wB0 = W1p[0], wB1 = W1p[1], wB2 = W1p[2], wB3 = W1p[3];
    float4 wC0 = W2p[0], wC1 = W2p[1], wC2 = W2p[2], wC3 = W2p[3];
    float4 wD0 = W3p[0], wD1 = W3p[1], wD2 = W3p[2], wD3 = W3p[3];
    PIN4(wA0); PIN4(wA1); PIN4(wA2); PIN4(wA3);
    PIN4(wB0); PIN4(wB1); PIN4(wB2); PIN4(wB3);
    PIN4(wC0); PIN4(wC1); PIN4(wC2); PIN4(wC3);
    PIN4(wD0); PIN4(wD1); PIN4(wD2); PIN4(wD3);

    // masked bias / x-weight (only chunk 0 injects them)
    float bgm0, bgm1, bgm2, bgm3, wxm0 = 0.f, wxm1 = 0.f, wxm2 = 0.f, wxm3 = 0.f;
    {
        const bool cz = (ck == 0);
        if (isL0) {
            bgm0 = cz ? (bih0[0*HD+j] + bhh0[0*HD+j]) : 0.f;
            bgm1 = cz ? (bih0[1*HD+j] + bhh0[1*HD+j]) : 0.f;
            bgm2 = cz ? (bih0[2*HD+j] + bhh0[2*HD+j]) : 0.f;
            bgm3 = cz ? (bih0[3*HD+j] + bhh0[3*HD+j]) : 0.f;
            wxm0 = cz ? Wih0[0*HD+j] : 0.f;
            wxm1 = cz ? Wih0[1*HD+j] : 0.f;
            wxm2 = cz ? Wih0[2*HD+j] : 0.f;
            wxm3 = cz ? Wih0[3*HD+j] : 0.f;
        } else {
            bgm0 = cz ? (bih1[0*HD+j] + bhh1[0*HD+j]) : 0.f;
            bgm1 = cz ? (bih1[1*HD+j] + bhh1[1*HD+j]) : 0.f;
            bgm2 = cz ? (bih1[2*HD+j] + bhh1[2*HD+j]) : 0.f;
            bgm3 = cz ? (bih1[3*HD+j] + bhh1[3*HD+j]) : 0.f;
        }
    }
    PIN1(bgm0); PIN1(bgm1); PIN1(bgm2); PIN1(bgm3);
    PIN1(wxm0); PIN1(wxm1); PIN1(wxm2); PIN1(wxm3);

    // per-thread LDS constants, hoisted: swizzled block offsets, parity-selectable
    // read pointers, and the two store addresses.
    const int o0 = swz(4 * ckk + 0);
    const int o1 = swz(4 * ckk + 1);
    const int o2 = swz(4 * ckk + 2);
    const int o3 = swz(4 * ckk + 3);
    const int rdBufBase = (ck < 4) ? H1_BASE : H2_BASE;   // isL0 has ck<4
    const int rdPhase   = (ck < 4) ? 1 : 0;               // h1 readers: (i+1)&1; h2: i&1
    const char* rpP0 = arena + rdBufBase + ((rdPhase & 1) << 10);        // i even
    const char* rpP1 = arena + rdBufBase + (((1 + rdPhase) & 1) << 10);  // i odd
    // store: L0 writes h1[i] at parity i&1; L1 writes h2[i-1] at parity (i+1)&1
    const int stBase  = isL0 ? H1_BASE : H2_BASE;
    const int stCore  = stBase + (rk << 8) + swz(j >> 2) + ((j & 3) << 2);
    char* const stP0 = arena + stCore + ((isL0 ? 0 : 1) << 10);          // i even
    char* const stP1 = arena + stCore + ((isL0 ? 1 : 0) << 10);          // i odd

    // zero both parities of h1 and h2 (swizzle is a bijection -> linear zero OK)
    for (int z = tid; z < 512; z += 768) {
        *(float*)(arena + H1_BASE + 4 * z) = 0.f;
        *(float*)(arena + H2_BASE + 4 * z) = 0.f;
    }

    const float* xp0 = x + (row0 + 0) * TT;
    const float* xp1 = x + (row0 + 1) * TT;
    const float* xp2 = x + (row0 + 2) * TT;
    const float* xp3 = x + (row0 + 3) * TT;
    float xn0 = 0.f, xn1 = 0.f, xn2 = 0.f, xn3 = 0.f;
    if (isL0) { xn0 = xp0[0]; xn1 = xp1[0]; xn2 = xp2[0]; xn3 = xp3[0]; }

    const float fcwj = fcW[j];
    float cc = 0.f, hlast = 0.f;

    __syncthreads();

    for (int i = 0; i <= TT; ++i) {
        const bool odd = (i & 1) != 0;
        const char* rp = odd ? rpP1 : rpP0;

        float a00, a01, a02, a03, a10, a11, a12, a13;
        float a20, a21, a22, a23, a30, a31, a32, a33;

        if (isL0) {
            const float xv0 = xn0, xv1 = xn1, xv2 = xn2, xv3 = xn3;
            const int inext = (i + 1 < TT) ? (i + 1) : (TT - 1);
            xn0 = xp0[inext]; xn1 = xp1[inext]; xn2 = xp2[inext]; xn3 = xp3[inext];
            a00 = __fmaf_rn(xv0, wxm0, bgm0); a01 = __fmaf_rn(xv0, wxm1, bgm1);
            a02 = __fmaf_rn(xv0, wxm2, bgm2); a03 = __fmaf_rn(xv0, wxm3, bgm3);
            a10 = __fmaf_rn(xv1, wxm0, bgm0); a11 = __fmaf_rn(xv1, wxm1, bgm1);
            a12 = __fmaf_rn(xv1, wxm2, bgm2); a13 = __fmaf_rn(xv1, wxm3, bgm3);
            a20 = __fmaf_rn(xv2, wxm0, bgm0); a21 = __fmaf_rn(xv2, wxm1, bgm1);
            a22 = __fmaf_rn(xv2, wxm2, bgm2); a23 = __fmaf_rn(xv2, wxm3, bgm3);
            a30 = __fmaf_rn(xv3, wxm0, bgm0); a31 = __fmaf_rn(xv3, wxm1, bgm1);
            a32 = __fmaf_rn(xv3, wxm2, bgm2); a33 = __fmaf_rn(xv3, wxm3, bgm3);
        } else {
            a00 = bgm0; a01 = bgm1; a02 = bgm2; a03 = bgm3;
            a10 = bgm0; a11 = bgm1; a12 = bgm2; a13 = bgm3;
            a20 = bgm0; a21 = bgm1; a22 = bgm2; a23 = bgm3;
            a30 = bgm0; a31 = bgm1; a32 = bgm2; a33 = bgm3;
        }

        ROWDOT(0, a00, a01, a02, a03)
        ROWDOT(1, a10, a11, a12, a13)
        ROWDOT(2, a20, a21, a22, a23)
        ROWDOT(3, a30, a31, a32, a33)

        // intra-quad reduction (xor1 + xor2) on the VALU via DPP quad_perm
        BF2D(a00) BF2D(a01) BF2D(a02) BF2D(a03)
        BF2D(a10) BF2D(a11) BF2D(a12) BF2D(a13)
        BF2D(a20) BF2D(a21) BF2D(a22) BF2D(a23)
        BF2D(a30) BF2D(a31) BF2D(a32) BF2D(a33)

        // select this lane's row FIRST (16 -> 4 values)...
        SEL4(e0, a00, a10, a20, a30)
        SEL4(e1, a01, a11, a21, a31)
        SEL4(e2, a02, a12, a22, a32)
        SEL4(e3, a03, a13, a23, a33)

        // ...then L1's cross-quad combine is only 4 swizzles (quad0 = h1-half, quad1 = h2-half)
        if (!isL0) {
            e0 += __shfl_xor(e0, 4, 64);
            e1 += __shfl_xor(e1, 4, 64);
            e2 += __shfl_xor(e2, 4, 64);
            e3 += __shfl_xor(e3, 4, 64);
        }

        if (isL0) {
            const float iv = fsig(e0), fv = fsig(e1), gv = ftanh_(e2), ov = fsig(e3);
            cc = __fmaf_rn(fv, cc, iv * gv);
            const float hh = ov * ftanh_(cc);
            *(float*)(odd ? stP1 : stP0) = hh;                 // h1[i]
        } else if (ck < 4 && i > 0) {
            const float iv = fsig(e0), fv = fsig(e1), gv = ftanh_(e2), ov = fsig(e3);
            cc = __fmaf_rn(fv, cc, iv * gv);
            hlast = ov * ftanh_(cc);
            *(float*)(odd ? stP1 : stP0) = hlast;              // h2[i-1]
        }
        __syncthreads();
    }

    // ---- FC: out[row] = sum_j h2[T-1][row][j] * fcW[j] + fcb ----
    if (!isL0 && ck < 4)
        *(float*)(arena + FCS_BASE + ((ck * HD + j) << 2)) = hlast * fcwj;
    __syncthreads();

    if (tid < 64) {
        const int r = tid >> 4, seg = tid & 15;
        const float4 v = ((const float4*)(arena + FCS_BASE))[r * 16 + seg];
        float s = (v.x + v.y) + (v.z + v.w);
        s += __shfl_xor(s, 1, 64);
        s += __shfl_xor(s, 2, 64);
        s += __shfl_xor(s, 4, 64);
        s += __shfl_xor(s, 8, 64);
        if (seg == 0) out[row0 + r] = s + fcb[0];
    }
}

extern "C" void kernel_launch(void* const* d_in, const int* in_sizes, int n_in,
                              void* d_out, int out_size, void* d_ws, size_t ws_size,
                              hipStream_t stream) {
    const float* x    = (const float*)d_in[0];
    const float* Wih0 = (const float*)d_in[1];
    const float* Whh0 = (const float*)d_in[2];
    const float* bih0 = (const float*)d_in[3];
    const float* bhh0 = (const float*)d_in[4];
    const float* Wih1 = (const float*)d_in[5];
    const float* Whh1 = (const float*)d_in[6];
    const float* bih1 = (const float*)d_in[7];
    const float* bhh1 = (const float*)d_in[8];
    const float* fcW  = (const float*)d_in[9];
    const float* fcb  = (const float*)d_in[10];
    float* out = (float*)d_out;

    lstm2_kernel<<<256, 768, 0, stream>>>(x, Wih0, Whh0, bih0, bhh0,
                                          Wih1, Whh1, bih1, bhh1,
                                          fcW, fcb, out);
}

// Round 6
// 4170.075 us; speedup vs baseline: 1.0212x; 1.0212x over previous
//
#include <hip/hip_runtime.h>

#define TT 2048
#define HD 64

// LDS arena byte map:
//   h1 : [0, 2048)      parity p, row r at (p*4+r)*256 B; 16B blocks XOR-swizzled
//   h2 : [2112, 4160)   same layout, +64B skew so h1+h2 chunk reads cover all 32 banks
//   fcs: [4160, 5184)
#define H1_BASE 0
#define H2_BASE 2112
#define FCS_BASE 4160

__device__ __forceinline__ float fsig(float x)  { return 1.0f / (1.0f + __expf(-x)); }
__device__ __forceinline__ float ftanh_(float x){ return 1.0f - 2.0f / (1.0f + __expf(2.0f * x)); }

// 16B-block swizzle within a 256B row: block index b in [0,16) -> byte offset
__device__ __forceinline__ int swz(int b) { return ((b ^ ((b >> 2) & 3)) << 4); }

// Pin a float4 into VGPRs (R4: VGPR=84 showed weights re-loaded from L2 each step).
#define PIN4(v) asm volatile("" : "+v"(v.x), "+v"(v.y), "+v"(v.z), "+v"(v.w))
#define PIN1(v) asm volatile("" : "+v"(v))

// DPP quad_perm add: pure VALU cross-lane, stays OFF the LDS pipe.
// 0xB1 = quad_perm[1,0,3,2] (xor 1), 0x4E = quad_perm[2,3,0,1] (xor 2).
template<int CTRL>
__device__ __forceinline__ float dpp_add(float v) {
    const int o = __builtin_amdgcn_update_dpp(0, __float_as_int(v), CTRL, 0xF, 0xF, true);
    return v + __int_as_float(o);
}
#define BF2D(v) { v = dpp_add<0xB1>(v); v = dpp_add<0x4E>(v); }

#define DOT16(acc, W0, W1, W2, W3) \
    acc = __fmaf_rn(W0.x, hv0.x, acc); acc = __fmaf_rn(W0.y, hv0.y, acc); \
    acc = __fmaf_rn(W0.z, hv0.z, acc); acc = __fmaf_rn(W0.w, hv0.w, acc); \
    acc = __fmaf_rn(W1.x, hv1.x, acc); acc = __fmaf_rn(W1.y, hv1.y, acc); \
    acc = __fmaf_rn(W1.z, hv1.z, acc); acc = __fmaf_rn(W1.w, hv1.w, acc); \
    acc = __fmaf_rn(W2.x, hv2.x, acc); acc = __fmaf_rn(W2.y, hv2.y, acc); \
    acc = __fmaf_rn(W2.z, hv2.z, acc); acc = __fmaf_rn(W2.w, hv2.w, acc); \
    acc = __fmaf_rn(W3.x, hv3.x, acc); acc = __fmaf_rn(W3.y, hv3.y, acc); \
    acc = __fmaf_rn(W3.z, hv3.z, acc); acc = __fmaf_rn(W3.w, hv3.w, acc);

#define ROWDOT(R, A0, A1, A2, A3) { \
    const float4 hv0 = *(const float4*)(rp + (R)*256 + o0); \
    const float4 hv1 = *(const float4*)(rp + (R)*256 + o1); \
    const float4 hv2 = *(const float4*)(rp + (R)*256 + o2); \
    const float4 hv3 = *(const float4*)(rp + (R)*256 + o3); \
    DOT16(A0, wA0, wA1, wA2, wA3); \
    DOT16(A1, wB0, wB1, wB2, wB3); \
    DOT16(A2, wC0, wC1, wC2, wC3); \
    DOT16(A3, wD0, wD1, wD2, wD3); }

// pick row=rk value out of the 4 row-accumulators (all lanes hold quad/full sums)
#define SEL4(e, x0, x1, x2, x3) \
    float e = x0; e = (rk == 1) ? x1 : e; e = (rk == 2) ? x2 : e; e = (rk == 3) ? x3 : e;

// Block = 768 threads, 4 batch rows per block. Grid = 256 blocks on 256 CUs ->
// exactly ONE block/CU can be resident, so cap waves/EU at 3 to hand the
// register allocator the full 170-VGPR budget (R5: default heuristic targeted
// 6 waves/EU -> 84 VGPRs -> spilled all weights to scratch every iteration).
//   waves 0-3  (tid 0..255):   layer0.  j=tid>>2 (unit), ck=tid&3  (16-wide K chunk of 64)
//   waves 4-11 (tid 256..767): layer1.  p=tid-256, j=p>>3, ck=p&7 (16-wide chunk of K=128=[h1|h2])
// Reduction: xor1+xor2 via DPP quad_perm (VALU); L1's xor4 via 4 ds_swizzle AFTER row-select.
// Pipeline: iter i does layer0 step i and layer1 step i-1; ONE barrier per iter.
__global__ __launch_bounds__(768)
__attribute__((amdgpu_waves_per_eu(3, 3)))
void lstm2_kernel(const float* __restrict__ x,
                  const float* __restrict__ Wih0,
                  const float* __restrict__ Whh0,
                  const float* __restrict__ bih0,
                  const float* __restrict__ bhh0,
                  const float* __restrict__ Wih1,
                  const float* __restrict__ Whh1,
                  const float* __restrict__ bih1,
                  const float* __restrict__ bhh1,
                  const float* __restrict__ fcW,
                  const float* __restrict__ fcb,
                  float* __restrict__ out)
{
    __shared__ __align__(16) float arena_f[1296];
    char* const arena = (char*)arena_f;

    const int tid  = threadIdx.x;
    const int row0 = blockIdx.x * 4;

    const bool isL0 = (tid < 256);
    const int  p    = isL0 ? tid : (tid - 256);
    const int  j    = isL0 ? (p >> 2) : (p >> 3);
    const int  ck   = isL0 ? (p & 3)  : (p & 7);
    const int  ckk  = (ck < 4) ? ck : (ck - 4);
    const int  rk   = ck & 3;                      // this lane's output row

    // ---- weights: 16 explicit float4 registers (64 VGPRs), no arrays ----
    const float* Wsrc;
    if (isL0)        Wsrc = Whh0;
    else if (ck < 4) Wsrc = Wih1;
    else             Wsrc = Whh1;
    const int kbase = 16 * ckk;
    const float4* W0p = (const float4*)(Wsrc + (0 * HD + j) * HD + kbase);
    const float4* W1p = (const float4*)(Wsrc + (1 * HD + j) * HD + kbase);
    const float4* W2p = (const float4*)(Wsrc + (2 * HD + j) * HD + kbase);
    const float4* W3p = (const float4*)(Wsrc + (3 * HD + j) * HD + kbase);
    float4 wA0 = W0p[0], wA1 = W0p[1], wA2 = W0p[2], wA3 = W0p[3];
    float4 wB0 = W1p[0], wB1 = W1p[1], wB2 = W1p[2], wB3 = W1p[3];
    float4 wC0 = W2p[0], wC1 = W2p[1], wC2 = W2p[2], wC3 = W2p[3];
    float4 wD0 = W3p[0], wD1 = W3p[1], wD2 = W3p[2], wD3 = W3p[3];
    PIN4(wA0); PIN4(wA1); PIN4(wA2); PIN4(wA3);
    PIN4(wB0); PIN4(wB1); PIN4(wB2); PIN4(wB3);
    PIN4(wC0); PIN4(wC1); PIN4(wC2); PIN4(wC3);
    PIN4(wD0); PIN4(wD1); PIN4(wD2); PIN4(wD3);

    // masked bias / x-weight (only chunk 0 injects them)
    float bgm0, bgm1, bgm2, bgm3, wxm0 = 0.f, wxm1 = 0.f, wxm2 = 0.f, wxm3 = 0.f;
    {
        const bool cz = (ck == 0);
        if (isL0) {
            bgm0 = cz ? (bih0[0*HD+j] + bhh0[0*HD+j]) : 0.f;
            bgm1 = cz ? (bih0[1*HD+j] + bhh0[1*HD+j]) : 0.f;
            bgm2 = cz ? (bih0[2*HD+j] + bhh0[2*HD+j]) : 0.f;
            bgm3 = cz ? (bih0[3*HD+j] + bhh0[3*HD+j]) : 0.f;
            wxm0 = cz ? Wih0[0*HD+j] : 0.f;
            wxm1 = cz ? Wih0[1*HD+j] : 0.f;
            wxm2 = cz ? Wih0[2*HD+j] : 0.f;
            wxm3 = cz ? Wih0[3*HD+j] : 0.f;
        } else {
            bgm0 = cz ? (bih1[0*HD+j] + bhh1[0*HD+j]) : 0.f;
            bgm1 = cz ? (bih1[1*HD+j] + bhh1[1*HD+j]) : 0.f;
            bgm2 = cz ? (bih1[2*HD+j] + bhh1[2*HD+j]) : 0.f;
            bgm3 = cz ? (bih1[3*HD+j] + bhh1[3*HD+j]) : 0.f;
        }
    }
    PIN1(bgm0); PIN1(bgm1); PIN1(bgm2); PIN1(bgm3);
    PIN1(wxm0); PIN1(wxm1); PIN1(wxm2); PIN1(wxm3);

    // per-thread LDS constants, hoisted: swizzled block offsets, parity-selectable
    // read pointers, and the two store addresses.
    const int o0 = swz(4 * ckk + 0);
    const int o1 = swz(4 * ckk + 1);
    const int o2 = swz(4 * ckk + 2);
    const int o3 = swz(4 * ckk + 3);
    const int rdBufBase = (ck < 4) ? H1_BASE : H2_BASE;   // isL0 has ck<4
    const int rdPhase   = (ck < 4) ? 1 : 0;               // h1 readers: (i+1)&1; h2: i&1
    const char* rpP0 = arena + rdBufBase + ((rdPhase & 1) << 10);        // i even
    const char* rpP1 = arena + rdBufBase + (((1 + rdPhase) & 1) << 10);  // i odd
    // store: L0 writes h1[i] at parity i&1; L1 writes h2[i-1] at parity (i+1)&1
    const int stBase  = isL0 ? H1_BASE : H2_BASE;
    const int stCore  = stBase + (rk << 8) + swz(j >> 2) + ((j & 3) << 2);
    char* const stP0 = arena + stCore + ((isL0 ? 0 : 1) << 10);          // i even
    char* const stP1 = arena + stCore + ((isL0 ? 1 : 0) << 10);          // i odd

    // zero both parities of h1 and h2 (swizzle is a bijection -> linear zero OK)
    for (int z = tid; z < 512; z += 768) {
        *(float*)(arena + H1_BASE + 4 * z) = 0.f;
        *(float*)(arena + H2_BASE + 4 * z) = 0.f;
    }

    const float* xp0 = x + (row0 + 0) * TT;
    const float* xp1 = x + (row0 + 1) * TT;
    const float* xp2 = x + (row0 + 2) * TT;
    const float* xp3 = x + (row0 + 3) * TT;
    float xn0 = 0.f, xn1 = 0.f, xn2 = 0.f, xn3 = 0.f;
    if (isL0) { xn0 = xp0[0]; xn1 = xp1[0]; xn2 = xp2[0]; xn3 = xp3[0]; }

    const float fcwj = fcW[j];
    float cc = 0.f, hlast = 0.f;

    __syncthreads();

    for (int i = 0; i <= TT; ++i) {
        const bool odd = (i & 1) != 0;
        const char* rp = odd ? rpP1 : rpP0;

        float a00, a01, a02, a03, a10, a11, a12, a13;
        float a20, a21, a22, a23, a30, a31, a32, a33;

        if (isL0) {
            const float xv0 = xn0, xv1 = xn1, xv2 = xn2, xv3 = xn3;
            const int inext = (i + 1 < TT) ? (i + 1) : (TT - 1);
            xn0 = xp0[inext]; xn1 = xp1[inext]; xn2 = xp2[inext]; xn3 = xp3[inext];
            a00 = __fmaf_rn(xv0, wxm0, bgm0); a01 = __fmaf_rn(xv0, wxm1, bgm1);
            a02 = __fmaf_rn(xv0, wxm2, bgm2); a03 = __fmaf_rn(xv0, wxm3, bgm3);
            a10 = __fmaf_rn(xv1, wxm0, bgm0); a11 = __fmaf_rn(xv1, wxm1, bgm1);
            a12 = __fmaf_rn(xv1, wxm2, bgm2); a13 = __fmaf_rn(xv1, wxm3, bgm3);
            a20 = __fmaf_rn(xv2, wxm0, bgm0); a21 = __fmaf_rn(xv2, wxm1, bgm1);
            a22 = __fmaf_rn(xv2, wxm2, bgm2); a23 = __fmaf_rn(xv2, wxm3, bgm3);
            a30 = __fmaf_rn(xv3, wxm0, bgm0); a31 = __fmaf_rn(xv3, wxm1, bgm1);
            a32 = __fmaf_rn(xv3, wxm2, bgm2); a33 = __fmaf_rn(xv3, wxm3, bgm3);
        } else {
            a00 = bgm0; a01 = bgm1; a02 = bgm2; a03 = bgm3;
            a10 = bgm0; a11 = bgm1; a12 = bgm2; a13 = bgm3;
            a20 = bgm0; a21 = bgm1; a22 = bgm2; a23 = bgm3;
            a30 = bgm0; a31 = bgm1; a32 = bgm2; a33 = bgm3;
        }

        ROWDOT(0, a00, a01, a02, a03)
        ROWDOT(1, a10, a11, a12, a13)
        ROWDOT(2, a20, a21, a22, a23)
        ROWDOT(3, a30, a31, a32, a33)

        // intra-quad reduction (xor1 + xor2) on the VALU via DPP quad_perm
        BF2D(a00) BF2D(a01) BF2D(a02) BF2D(a03)
        BF2D(a10) BF2D(a11) BF2D(a12) BF2D(a13)
        BF2D(a20) BF2D(a21) BF2D(a22) BF2D(a23)
        BF2D(a30) BF2D(a31) BF2D(a32) BF2D(a33)

        // select this lane's row FIRST (16 -> 4 values)...
        SEL4(e0, a00, a10, a20, a30)
        SEL4(e1, a01, a11, a21, a31)
        SEL4(e2, a02, a12, a22, a32)
        SEL4(e3, a03, a13, a23, a33)

        // ...then L1's cross-quad combine is only 4 swizzles (quad0 = h1-half, quad1 = h2-half)
        if (!isL0) {
            e0 += __shfl_xor(e0, 4, 64);
            e1 += __shfl_xor(e1, 4, 64);
            e2 += __shfl_xor(e2, 4, 64);
            e3 += __shfl_xor(e3, 4, 64);
        }

        if (isL0) {
            const float iv = fsig(e0), fv = fsig(e1), gv = ftanh_(e2), ov = fsig(e3);
            cc = __fmaf_rn(fv, cc, iv * gv);
            const float hh = ov * ftanh_(cc);
            *(float*)(odd ? stP1 : stP0) = hh;                 // h1[i]
        } else if (ck < 4 && i > 0) {
            const float iv = fsig(e0), fv = fsig(e1), gv = ftanh_(e2), ov = fsig(e3);
            cc = __fmaf_rn(fv, cc, iv * gv);
            hlast = ov * ftanh_(cc);
            *(float*)(odd ? stP1 : stP0) = hlast;              // h2[i-1]
        }
        __syncthreads();
    }

    // ---- FC: out[row] = sum_j h2[T-1][row][j] * fcW[j] + fcb ----
    if (!isL0 && ck < 4)
        *(float*)(arena + FCS_BASE + ((ck * HD + j) << 2)) = hlast * fcwj;
    __syncthreads();

    if (tid < 64) {
        const int r = tid >> 4, seg = tid & 15;
        const float4 v = ((const float4*)(arena + FCS_BASE))[r * 16 + seg];
        float s = (v.x + v.y) + (v.z + v.w);
        s += __shfl_xor(s, 1, 64);
        s += __shfl_xor(s, 2, 64);
        s += __shfl_xor(s, 4, 64);
        s += __shfl_xor(s, 8, 64);
        if (seg == 0) out[row0 + r] = s + fcb[0];
    }
}

extern "C" void kernel_launch(void* const* d_in, const int* in_sizes, int n_in,
                              void* d_out, int out_size, void* d_ws, size_t ws_size,
                              hipStream_t stream) {
    const float* x    = (const float*)d_in[0];
    const float* Wih0 = (const float*)d_in[1];
    const float* Whh0 = (const float*)d_in[2];
    const float* bih0 = (const float*)d_in[3];
    const float* bhh0 = (const float*)d_in[4];
    const float* Wih1 = (const float*)d_in[5];
    const float* Whh1 = (const float*)d_in[6];
    const float* bih1 = (const float*)d_in[7];
    const float* bhh1 = (const float*)d_in[8];
    const float* fcW  = (const float*)d_in[9];
    const float* fcb  = (const float*)d_in[10];
    float* out = (float*)d_out;

    lstm2_kernel<<<256, 768, 0, stream>>>(x, Wih0, Whh0, bih0, bhh0,
                                          Wih1, Whh1, bih1, bhh1,
                                          fcW, fcb, out);
}

// Round 7
// 4152.504 us; speedup vs baseline: 1.0256x; 1.0042x over previous
//
#include <hip/hip_runtime.h>

#define TT 2048
#define HD 64

// LDS arena byte map:
//   h1 : [0, 2048)      parity p, row r at (p*4+r)*256 B; 16B blocks XOR-swizzled
//   h2 : [2112, 4160)   same layout, +64B skew so h1+h2 chunk reads cover all 32 banks
//   fcs: [4160, 5184)
#define H1_BASE 0
#define H2_BASE 2112
#define FCS_BASE 4160

__device__ __forceinline__ float fsig(float x)  { return 1.0f / (1.0f + __expf(-x)); }
__device__ __forceinline__ float ftanh_(float x){ return 1.0f - 2.0f / (1.0f + __expf(2.0f * x)); }

// 16B-block swizzle within a 256B row: block index b in [0,16) -> byte offset
__device__ __forceinline__ int swz(int b) { return ((b ^ ((b >> 2) & 3)) << 4); }

// Pin a float4 into VGPRs (R4: VGPR=84 showed weights re-loaded from L2 each step).
#define PIN4(v) asm volatile("" : "+v"(v.x), "+v"(v.y), "+v"(v.z), "+v"(v.w))
#define PIN1(v) asm volatile("" : "+v"(v))

// DPP quad_perm add: pure VALU cross-lane, stays OFF the LDS pipe.
// 0xB1 = quad_perm[1,0,3,2] (xor 1), 0x4E = quad_perm[2,3,0,1] (xor 2).
template<int CTRL>
__device__ __forceinline__ float dpp_add(float v) {
    const int o = __builtin_amdgcn_update_dpp(0, __float_as_int(v), CTRL, 0xF, 0xF, true);
    return v + __int_as_float(o);
}
#define BF2D(v) { v = dpp_add<0xB1>(v); v = dpp_add<0x4E>(v); }

#define DOT16(acc, W0, W1, W2, W3) \
    acc = __fmaf_rn(W0.x, hv0.x, acc); acc = __fmaf_rn(W0.y, hv0.y, acc); \
    acc = __fmaf_rn(W0.z, hv0.z, acc); acc = __fmaf_rn(W0.w, hv0.w, acc); \
    acc = __fmaf_rn(W1.x, hv1.x, acc); acc = __fmaf_rn(W1.y, hv1.y, acc); \
    acc = __fmaf_rn(W1.z, hv1.z, acc); acc = __fmaf_rn(W1.w, hv1.w, acc); \
    acc = __fmaf_rn(W2.x, hv2.x, acc); acc = __fmaf_rn(W2.y, hv2.y, acc); \
    acc = __fmaf_rn(W2.z, hv2.z, acc); acc = __fmaf_rn(W2.w, hv2.w, acc); \
    acc = __fmaf_rn(W3.x, hv3.x, acc); acc = __fmaf_rn(W3.y, hv3.y, acc); \
    acc = __fmaf_rn(W3.z, hv3.z, acc); acc = __fmaf_rn(W3.w, hv3.w, acc);

#define ROWDOT(R, A0, A1, A2, A3) { \
    const float4 hv0 = *(const float4*)(rp + (R)*256 + o0); \
    const float4 hv1 = *(const float4*)(rp + (R)*256 + o1); \
    const float4 hv2 = *(const float4*)(rp + (R)*256 + o2); \
    const float4 hv3 = *(const float4*)(rp + (R)*256 + o3); \
    DOT16(A0, wA0, wA1, wA2, wA3); \
    DOT16(A1, wB0, wB1, wB2, wB3); \
    DOT16(A2, wC0, wC1, wC2, wC3); \
    DOT16(A3, wD0, wD1, wD2, wD3); }

// pick row=rk value out of the 4 row-accumulators (all lanes hold quad/full sums)
#define SEL4(e, x0, x1, x2, x3) \
    float e = x0; e = (rk == 1) ? x1 : e; e = (rk == 2) ? x2 : e; e = (rk == 3) ? x3 : e;

// Block = 768 threads, 4 batch rows per block. Grid = 256 blocks on 256 CUs ->
// exactly ONE block/CU resident, 3 waves/EU max. R5/R6 showed waves-per-eu
// attributes do NOT move the allocator off its 6-waves/EU budget (84 VGPRs ->
// weights spilled every step). amdgpu_num_vgpr(160) overrides the budget
// computation directly (read in getMaxNumVGPRs), giving the RA room for the
// 64 weight VGPRs + accumulators with zero spill at the only occupancy the
// grid can achieve anyway.
//   waves 0-3  (tid 0..255):   layer0.  j=tid>>2 (unit), ck=tid&3  (16-wide K chunk of 64)
//   waves 4-11 (tid 256..767): layer1.  p=tid-256, j=p>>3, ck=p&7 (16-wide chunk of K=128=[h1|h2])
// Reduction: xor1+xor2 via DPP quad_perm (VALU); L1's xor4 via 4 ds_swizzle AFTER row-select.
// Pipeline: iter i does layer0 step i and layer1 step i-1; ONE barrier per iter.
__global__ __launch_bounds__(768)
__attribute__((amdgpu_num_vgpr(160)))
__attribute__((amdgpu_waves_per_eu(3, 3)))
void lstm2_kernel(const float* __restrict__ x,
                  const float* __restrict__ Wih0,
                  const float* __restrict__ Whh0,
                  const float* __restrict__ bih0,
                  const float* __restrict__ bhh0,
                  const float* __restrict__ Wih1,
                  const float* __restrict__ Whh1,
                  const float* __restrict__ bih1,
                  const float* __restrict__ bhh1,
                  const float* __restrict__ fcW,
                  const float* __restrict__ fcb,
                  float* __restrict__ out)
{
    __shared__ __align__(16) float arena_f[1296];
    char* const arena = (char*)arena_f;

    const int tid  = threadIdx.x;
    const int row0 = blockIdx.x * 4;

    const bool isL0 = (tid < 256);
    const int  p    = isL0 ? tid : (tid - 256);
    const int  j    = isL0 ? (p >> 2) : (p >> 3);
    const int  ck   = isL0 ? (p & 3)  : (p & 7);
    const int  ckk  = (ck < 4) ? ck : (ck - 4);
    const int  rk   = ck & 3;                      // this lane's output row

    // ---- weights: 16 explicit float4 registers (64 VGPRs), no arrays ----
    const float* Wsrc;
    if (isL0)        Wsrc = Whh0;
    else if (ck < 4) Wsrc = Wih1;
    else             Wsrc = Whh1;
    const int kbase = 16 * ckk;
    const float4* W0p = (const float4*)(Wsrc + (0 * HD + j) * HD + kbase);
    const float4* W1p = (const float4*)(Wsrc + (1 * HD + j) * HD + kbase);
    const float4* W2p = (const float4*)(Wsrc + (2 * HD + j) * HD + kbase);
    const float4* W3p = (const float4*)(Wsrc + (3 * HD + j) * HD + kbase);
    float4 wA0 = W0p[0], wA1 = W0p[1], wA2 = W0p[2], wA3 = W0p[3];
    float4 wB0 = W1p[0], wB1 = W1p[1], wB2 = W1p[2], wB3 = W1p[3];
    float4 wC0 = W2p[0], wC1 = W2p[1], wC2 = W2p[2], wC3 = W2p[3];
    float4 wD0 = W3p[0], wD1 = W3p[1], wD2 = W3p[2], wD3 = W3p[3];
    PIN4(wA0); PIN4(wA1); PIN4(wA2); PIN4(wA3);
    PIN4(wB0); PIN4(wB1); PIN4(wB2); PIN4(wB3);
    PIN4(wC0); PIN4(wC1); PIN4(wC2); PIN4(wC3);
    PIN4(wD0); PIN4(wD1); PIN4(wD2); PIN4(wD3);

    // masked bias / x-weight (only chunk 0 injects them)
    float bgm0, bgm1, bgm2, bgm3, wxm0 = 0.f, wxm1 = 0.f, wxm2 = 0.f, wxm3 = 0.f;
    {
        const bool cz = (ck == 0);
        if (isL0) {
            bgm0 = cz ? (bih0[0*HD+j] + bhh0[0*HD+j]) : 0.f;
            bgm1 = cz ? (bih0[1*HD+j] + bhh0[1*HD+j]) : 0.f;
            bgm2 = cz ? (bih0[2*HD+j] + bhh0[2*HD+j]) : 0.f;
            bgm3 = cz ? (bih0[3*HD+j] + bhh0[3*HD+j]) : 0.f;
            wxm0 = cz ? Wih0[0*HD+j] : 0.f;
            wxm1 = cz ? Wih0[1*HD+j] : 0.f;
            wxm2 = cz ? Wih0[2*HD+j] : 0.f;
            wxm3 = cz ? Wih0[3*HD+j] : 0.f;
        } else {
            bgm0 = cz ? (bih1[0*HD+j] + bhh1[0*HD+j]) : 0.f;
            bgm1 = cz ? (bih1[1*HD+j] + bhh1[1*HD+j]) : 0.f;
            bgm2 = cz ? (bih1[2*HD+j] + bhh1[2*HD+j]) : 0.f;
            bgm3 = cz ? (bih1[3*HD+j] + bhh1[3*HD+j]) : 0.f;
        }
    }
    PIN1(bgm0); PIN1(bgm1); PIN1(bgm2); PIN1(bgm3);
    PIN1(wxm0); PIN1(wxm1); PIN1(wxm2); PIN1(wxm3);

    // per-thread LDS constants, hoisted: swizzled block offsets, parity-selectable
    // read pointers, and the two store addresses.
    const int o0 = swz(4 * ckk + 0);
    const int o1 = swz(4 * ckk + 1);
    const int o2 = swz(4 * ckk + 2);
    const int o3 = swz(4 * ckk + 3);
    const int rdBufBase = (ck < 4) ? H1_BASE : H2_BASE;   // isL0 has ck<4
    const int rdPhase   = (ck < 4) ? 1 : 0;               // h1 readers: (i+1)&1; h2: i&1
    const char* rpP0 = arena + rdBufBase + ((rdPhase & 1) << 10);        // i even
    const char* rpP1 = arena + rdBufBase + (((1 + rdPhase) & 1) << 10);  // i odd
    // store: L0 writes h1[i] at parity i&1; L1 writes h2[i-1] at parity (i+1)&1
    const int stBase  = isL0 ? H1_BASE : H2_BASE;
    const int stCore  = stBase + (rk << 8) + swz(j >> 2) + ((j & 3) << 2);
    char* const stP0 = arena + stCore + ((isL0 ? 0 : 1) << 10);          // i even
    char* const stP1 = arena + stCore + ((isL0 ? 1 : 0) << 10);          // i odd

    // zero both parities of h1 and h2 (swizzle is a bijection -> linear zero OK)
    for (int z = tid; z < 512; z += 768) {
        *(float*)(arena + H1_BASE + 4 * z) = 0.f;
        *(float*)(arena + H2_BASE + 4 * z) = 0.f;
    }

    const float* xp0 = x + (row0 + 0) * TT;
    const float* xp1 = x + (row0 + 1) * TT;
    const float* xp2 = x + (row0 + 2) * TT;
    const float* xp3 = x + (row0 + 3) * TT;
    float xn0 = 0.f, xn1 = 0.f, xn2 = 0.f, xn3 = 0.f;
    if (isL0) { xn0 = xp0[0]; xn1 = xp1[0]; xn2 = xp2[0]; xn3 = xp3[0]; }

    const float fcwj = fcW[j];
    float cc = 0.f, hlast = 0.f;

    __syncthreads();

    for (int i = 0; i <= TT; ++i) {
        const bool odd = (i & 1) != 0;
        const char* rp = odd ? rpP1 : rpP0;

        float a00, a01, a02, a03, a10, a11, a12, a13;
        float a20, a21, a22, a23, a30, a31, a32, a33;

        if (isL0) {
            const float xv0 = xn0, xv1 = xn1, xv2 = xn2, xv3 = xn3;
            const int inext = (i + 1 < TT) ? (i + 1) : (TT - 1);
            xn0 = xp0[inext]; xn1 = xp1[inext]; xn2 = xp2[inext]; xn3 = xp3[inext];
            a00 = __fmaf_rn(xv0, wxm0, bgm0); a01 = __fmaf_rn(xv0, wxm1, bgm1);
            a02 = __fmaf_rn(xv0, wxm2, bgm2); a03 = __fmaf_rn(xv0, wxm3, bgm3);
            a10 = __fmaf_rn(xv1, wxm0, bgm0); a11 = __fmaf_rn(xv1, wxm1, bgm1);
            a12 = __fmaf_rn(xv1, wxm2, bgm2); a13 = __fmaf_rn(xv1, wxm3, bgm3);
            a20 = __fmaf_rn(xv2, wxm0, bgm0); a21 = __fmaf_rn(xv2, wxm1, bgm1);
            a22 = __fmaf_rn(xv2, wxm2, bgm2); a23 = __fmaf_rn(xv2, wxm3, bgm3);
            a30 = __fmaf_rn(xv3, wxm0, bgm0); a31 = __fmaf_rn(xv3, wxm1, bgm1);
            a32 = __fmaf_rn(xv3, wxm2, bgm2); a33 = __fmaf_rn(xv3, wxm3, bgm3);
        } else {
            a00 = bgm0; a01 = bgm1; a02 = bgm2; a03 = bgm3;
            a10 = bgm0; a11 = bgm1; a12 = bgm2; a13 = bgm3;
            a20 = bgm0; a21 = bgm1; a22 = bgm2; a23 = bgm3;
            a30 = bgm0; a31 = bgm1; a32 = bgm2; a33 = bgm3;
        }

        ROWDOT(0, a00, a01, a02, a03)
        ROWDOT(1, a10, a11, a12, a13)
        ROWDOT(2, a20, a21, a22, a23)
        ROWDOT(3, a30, a31, a32, a33)

        // intra-quad reduction (xor1 + xor2) on the VALU via DPP quad_perm
        BF2D(a00) BF2D(a01) BF2D(a02) BF2D(a03)
        BF2D(a10) BF2D(a11) BF2D(a12) BF2D(a13)
        BF2D(a20) BF2D(a21) BF2D(a22) BF2D(a23)
        BF2D(a30) BF2D(a31) BF2D(a32) BF2D(a33)

        // select this lane's row FIRST (16 -> 4 values)...
        SEL4(e0, a00, a10, a20, a30)
        SEL4(e1, a01, a11, a21, a31)
        SEL4(e2, a02, a12, a22, a32)
        SEL4(e3, a03, a13, a23, a33)

        // ...then L1's cross-quad combine is only 4 swizzles (quad0 = h1-half, quad1 = h2-half)
        if (!isL0) {
            e0 += __shfl_xor(e0, 4, 64);
            e1 += __shfl_xor(e1, 4, 64);
            e2 += __shfl_xor(e2, 4, 64);
            e3 += __shfl_xor(e3, 4, 64);
        }

        if (isL0) {
            const float iv = fsig(e0), fv = fsig(e1), gv = ftanh_(e2), ov = fsig(e3);
            cc = __fmaf_rn(fv, cc, iv * gv);
            const float hh = ov * ftanh_(cc);
            *(float*)(odd ? stP1 : stP0) = hh;                 // h1[i]
        } else if (ck < 4 && i > 0) {
            const float iv = fsig(e0), fv = fsig(e1), gv = ftanh_(e2), ov = fsig(e3);
            cc = __fmaf_rn(fv, cc, iv * gv);
            hlast = ov * ftanh_(cc);
            *(float*)(odd ? stP1 : stP0) = hlast;              // h2[i-1]
        }
        __syncthreads();
    }

    // ---- FC: out[row] = sum_j h2[T-1][row][j] * fcW[j] + fcb ----
    if (!isL0 && ck < 4)
        *(float*)(arena + FCS_BASE + ((ck * HD + j) << 2)) = hlast * fcwj;
    __syncthreads();

    if (tid < 64) {
        const int r = tid >> 4, seg = tid & 15;
        const float4 v = ((const float4*)(arena + FCS_BASE))[r * 16 + seg];
        float s = (v.x + v.y) + (v.z + v.w);
        s += __shfl_xor(s, 1, 64);
        s += __shfl_xor(s, 2, 64);
        s += __shfl_xor(s, 4, 64);
        s += __shfl_xor(s, 8, 64);
        if (seg == 0) out[row0 + r] = s + fcb[0];
    }
}

extern "C" void kernel_launch(void* const* d_in, const int* in_sizes, int n_in,
                              void* d_out, int out_size, void* d_ws, size_t ws_size,
                              hipStream_t stream) {
    const float* x    = (const float*)d_in[0];
    const float* Wih0 = (const float*)d_in[1];
    const float* Whh0 = (const float*)d_in[2];
    const float* bih0 = (const float*)d_in[3];
    const float* bhh0 = (const float*)d_in[4];
    const float* Wih1 = (const float*)d_in[5];
    const float* Whh1 = (const float*)d_in[6];
    const float* bih1 = (const float*)d_in[7];
    const float* bhh1 = (const float*)d_in[8];
    const float* fcW  = (const float*)d_in[9];
    const float* fcb  = (const float*)d_in[10];
    float* out = (float*)d_out;

    lstm2_kernel<<<256, 768, 0, stream>>>(x, Wih0, Whh0, bih0, bhh0,
                                          Wih1, Whh1, bih1, bhh1,
                                          fcW, fcb, out);
}